// Round 10
// baseline (178.320 us; speedup 1.0000x reference)
//
#include <hip/hip_runtime.h>
#include <hip/hip_bf16.h>

// Problem constants
#define NB   64
#define NCDD 5
#define NHIS 100
#define ND   256
#define NK   10
#define TLD  23040          // T*L*D = 30*3*256
#define THRESH 0.1f
#define NEG_INF (-3.402823466e38f)
#define NROWS_HIS 6400      // 64*100
#define NROWS_CDD 320       // 64*5

typedef float f32x4 __attribute__((ext_vector_type(4)));

// ---------------------------------------------------------------------------
// Kernel 1: BYTE-IDENTICAL to R8/R9 (control).
// ---------------------------------------------------------------------------
__global__ __launch_bounds__(256) void proj_norm_all(
    const float* __restrict__ his_repr,
    const float* __restrict__ cdd_repr,
    const float* __restrict__ W,
    const float* __restrict__ bvec,
    float* __restrict__ Yall)
{
    __shared__ float red[4][8];
    const int r0  = blockIdx.x * 8;
    const int tid = threadIdx.x;
    const int sub = tid & 3;           // k-slice within a 4-lane group
    const int grp = tid >> 2;          // 0..63: column group (block-wide)
    const int wave = tid >> 6, lane = tid & 63;

    const float* __restrict__ X = (r0 < NROWS_HIS)
        ? (his_repr + (size_t)r0 * ND)
        : (cdd_repr + (size_t)(r0 - NROWS_HIS) * ND);

    float acc[4][8];
#pragma unroll
    for (int p = 0; p < 4; ++p)
#pragma unroll
        for (int r = 0; r < 8; ++r) acc[p][r] = 0.f;

#pragma unroll 4
    for (int i = 0; i < 16; ++i) {
        const int kb = sub * 4 + 16 * i;
        float4 x4[8];
#pragma unroll
        for (int r = 0; r < 8; ++r)
            x4[r] = *(const float4*)(X + (size_t)r * ND + kb);
#pragma unroll
        for (int p = 0; p < 4; ++p) {
            const int d = p * 64 + grp;
            const float4 w4 = *(const float4*)(W + (size_t)d * ND + kb);
#pragma unroll
            for (int r = 0; r < 8; ++r)
                acc[p][r] += w4.x * x4[r].x + w4.y * x4[r].y
                           + w4.z * x4[r].z + w4.w * x4[r].w;
        }
    }

#pragma unroll
    for (int p = 0; p < 4; ++p)
#pragma unroll
        for (int r = 0; r < 8; ++r) {
            float v = acc[p][r];
            v += __shfl_xor(v, 1);
            v += __shfl_xor(v, 2);
            acc[p][r] = v;
        }

    float bias[4];
#pragma unroll
    for (int p = 0; p < 4; ++p) bias[p] = bvec[p * 64 + grp];

    float ss[8];
#pragma unroll
    for (int r = 0; r < 8; ++r) {
        float t = 0.f;
#pragma unroll
        for (int p = 0; p < 4; ++p) {
            const float y = acc[p][r] + bias[p];
            acc[p][r] = y;
            t += y * y;
        }
        for (int off = 32; off; off >>= 1) t += __shfl_xor(t, off);
        ss[r] = t;
    }
    if (lane == 0) {
#pragma unroll
        for (int r = 0; r < 8; ++r) red[wave][r] = ss[r];
    }
    __syncthreads();

#pragma unroll
    for (int r = 0; r < 8; ++r) {
        const float s = 0.25f * (red[0][r] + red[1][r] + red[2][r] + red[3][r]);
        const float scale = 1.0f / fmaxf(sqrtf(s), 1e-12f);
        if (sub == 0) {
#pragma unroll
            for (int p = 0; p < 4; ++p)
                Yall[(size_t)(r0 + r) * ND + p * 64 + grp] = acc[p][r] * scale;
        }
    }
}

// ---------------------------------------------------------------------------
// Kernel 2 (fused attn+topk+gather): one block per g=(b,c,k).
// Prologue (redundant per block, bitwise-identical across the 10 k-blocks
// of a (b,c) -> consistent & deterministic):
//   - 100 dots cdd_p[b,c]·his_p[b,h]: 4-lane groups, group grp handles
//     h=grp and h=grp+64; all reads L2-resident (his_p slice per XCD ~800KB).
//   - wave 0 runs the exact top-10 butterfly (lax.top_k: descending,
//     lowest index on ties), stores 10 picks in LDS.
// Then block uses pick k: writes idx output, and copies/scales its 92KB row
// (copy body BYTE-IDENTICAL to R9: 22+tail reg-preload max-MLP).
// Eliminates the attn kernel + one launch gap from the critical path.
// ---------------------------------------------------------------------------
__global__ __launch_bounds__(256) void attn_gather_kernel(
    const float* __restrict__ cdd_p,
    const float* __restrict__ his_p,
    const float* __restrict__ his_emb,
    float* __restrict__ out_idx_f,
    float* __restrict__ out)
{
    __shared__ float attn_s[128];
    __shared__ float pick_w[NK];
    __shared__ int   pick_i[NK];

    const int orig = blockIdx.x;
    const int g = (orig & 7) * 400 + (orig >> 3);   // XCD-chunked (bijective)
    const int b = g / (NCDD * NK);
    const int c = (g / NK) % NCDD;
    const int k = g % NK;
    const int tid = threadIdx.x;
    const int sub = tid & 3, grp = tid >> 2;        // 64 groups
    const int wave = tid >> 6, lane = tid & 63;

    // ---- Phase 1: attention dots for (b,c) ----
    const float* __restrict__ crow = cdd_p + ((size_t)b * NCDD + c) * ND;
    const float* __restrict__ hbase = his_p + (size_t)b * NHIS * ND;
    {
        const int h0 = grp, h1 = grp + 64;
        const float* __restrict__ h0row = hbase + (size_t)h0 * ND;
        const float* __restrict__ h1row = hbase + (size_t)h1 * ND;
        float a0 = 0.f, a1 = 0.f;
#pragma unroll
        for (int i = 0; i < 16; ++i) {
            const int kb = sub * 4 + 16 * i;
            const float4 cv = *(const float4*)(crow + kb);
            const float4 v0 = *(const float4*)(h0row + kb);
            a0 += cv.x * v0.x + cv.y * v0.y + cv.z * v0.z + cv.w * v0.w;
            if (h1 < NHIS) {
                const float4 v1 = *(const float4*)(h1row + kb);
                a1 += cv.x * v1.x + cv.y * v1.y + cv.z * v1.z + cv.w * v1.w;
            }
        }
        a0 += __shfl_xor(a0, 1); a0 += __shfl_xor(a0, 2);
        a1 += __shfl_xor(a1, 1); a1 += __shfl_xor(a1, 2);
        if (sub == 0) {
            attn_s[h0] = a0;
            if (h1 < NHIS) attn_s[h1] = a1;
        }
    }
    __syncthreads();

    // ---- Phase 2: exact top-10 (wave 0) ----
    if (wave == 0) {
        float v0 = attn_s[lane];
        float v1 = (lane + 64 < NHIS) ? attn_s[lane + 64] : NEG_INF;
#pragma unroll
        for (int kk = 0; kk < NK; ++kk) {
            float lv; int li;
            if (v1 > v0) { lv = v1; li = lane + 64; }
            else         { lv = v0; li = lane; }            // tie -> lower idx
            for (int off = 1; off < 64; off <<= 1) {
                const float ov = __shfl_xor(lv, off);
                const int   oi = __shfl_xor(li, off);
                if (ov > lv || (ov == lv && oi < li)) { lv = ov; li = oi; }
            }
            if (lane == 0) {
                pick_i[kk] = li;
                pick_w[kk] = (lv < THRESH) ? 0.0f : lv;
            }
            if (li == lane)            v0 = NEG_INF;
            else if (li == lane + 64)  v1 = NEG_INF;
        }
    }
    __syncthreads();

    const int   idx = pick_i[k];
    const float w   = pick_w[k];
    if (tid == 0) out_idx_f[g] = (float)idx;

    // ---- Phase 3: copy/scale (byte-identical body to R9) ----
    f32x4* __restrict__ dst = (f32x4*)(out + (size_t)g * TLD);

    if (w == 0.0f) {
        const f32x4 z = {0.f, 0.f, 0.f, 0.f};
#pragma unroll
        for (int it = 0; it < 22; ++it) dst[tid + it * 256] = z;
        if (tid < 128) dst[22 * 256 + tid] = z;
        return;
    }

    const f32x4* __restrict__ src =
        (const f32x4*)(his_emb + ((size_t)b * NHIS + idx) * TLD);

    f32x4 v[22];
    f32x4 vt;
#pragma unroll
    for (int j = 0; j < 22; ++j) v[j] = src[tid + j * 256];
    const bool tail = (tid < 128);
    if (tail) vt = src[22 * 256 + tid];

#pragma unroll
    for (int j = 0; j < 22; ++j) dst[tid + j * 256] = v[j] * w;
    if (tail) dst[22 * 256 + tid] = vt * w;
}

// ---------------------------------------------------------------------------
extern "C" void kernel_launch(void* const* d_in, const int* in_sizes, int n_in,
                              void* d_out, int out_size, void* d_ws, size_t ws_size,
                              hipStream_t stream)
{
    const float* cdd_repr = (const float*)d_in[0];   // (64,5,256)
    const float* his_repr = (const float*)d_in[1];   // (64,100,256)
    const float* his_emb  = (const float*)d_in[2];   // (64,100,30,3,256)
    const float* W_sel    = (const float*)d_in[3];   // (256,256)
    const float* b_sel    = (const float*)d_in[4];   // (256,)
    float* out = (float*)d_out;

    // Workspace layout
    char* ws = (char*)d_ws;
    float* Yall  = (float*)ws;                       // 6720 rows * 256 * 4
    float* his_p = Yall;                             // rows [0, 6400)
    float* cdd_p = Yall + (size_t)NROWS_HIS * ND;    // rows [6400, 6720)

    // Output: his_activated [73,728,000] then idx [3200] (as float values)
    float* out_idx_f = out + (size_t)NB * NCDD * NK * TLD;

    proj_norm_all<<<(NROWS_HIS + NROWS_CDD) / 8, 256, 0, stream>>>(
        his_repr, cdd_repr, W_sel, b_sel, Yall);
    attn_gather_kernel<<<NB * NCDD * NK, 256, 0, stream>>>(
        cdd_p, his_p, his_emb, out_idx_f, out);
}